// Round 7
// baseline (27.031 us; speedup 1.0000x reference)
//
#include <hip/hip_runtime.h>
#include <cstdint>
#include <cstddef>

#define MM 36
#define NP 10
#define BLOCK 1024          // probe: 512 workgroups instead of 2048 (CP dispatch-rate test)
#define GPB (BLOCK / 16)    // 64 batches (16-lane groups) per block
#define WPB (BLOCK / 64)    // 16 waves per block

// ---- DPP helpers: 16-lane butterfly reduce ----
template<int CTRL>
__device__ __forceinline__ float dpp_movf(float x) {
    return __int_as_float(__builtin_amdgcn_update_dpp(
        0, __float_as_int(x), CTRL, 0xF, 0xF, true));
}
__device__ __forceinline__ float rowmax16(float x) {
    x = fmaxf(x, dpp_movf<0xB1>(x));   // xor 1
    x = fmaxf(x, dpp_movf<0x4E>(x));   // xor 2
    x = fmaxf(x, dpp_movf<0x141>(x));  // row_half_mirror (fold 8)
    x = fmaxf(x, dpp_movf<0x140>(x));  // row_mirror      (fold 16)
    return x;
}
__device__ __forceinline__ float rowsum16(float x) {
    x += dpp_movf<0xB1>(x);
    x += dpp_movf<0x4E>(x);
    x += dpp_movf<0x141>(x);
    x += dpp_movf<0x140>(x);
    return x;
}

// x in [0,1]; 17-entry table (ip==16 only at x==1: frac==0, returns cs[16] exactly)
__device__ __forceinline__ float pwl17(const float2* __restrict__ T, float x) {
    float xd = x * 16.0f;
    float fip = floorf(xd);
    float frac = xd - fip;
    int ip = (int)fminf(fip, 16.0f);
    float2 t = T[ip];
    return fmaf(frac, t.y, t.x);
}

__global__ __launch_bounds__(BLOCK) void count_kernel(
    const float* __restrict__ boxes,      // [B,4,36]
    const float* __restrict__ attention,  // [B,36]
    const float* __restrict__ fw,         // [8,17]
    float* __restrict__ out,              // [B,11]
    int B)
{
    __shared__ float2 Tw[WPB][4][17];     // per-wave: f0, f2, f5, f7
    __shared__ float4 T16w[WPB][17];      // per-wave packed (cs1,nw1',cs6,nw6')
    __shared__ float  boxrow[GPB][4 * MM];
    __shared__ float4 propA[GPB][NP];     // y1,x1,y2,x2
    __shared__ float2 propB[GPB][NP];     // area, satt
    __shared__ __align__(8) float invl[GPB][NP];

    const int tid  = threadIdx.x;
    const int lane = tid & 63;
    const int w    = tid >> 6;
    const int l    = tid & 15;
    const int g    = tid >> 4;
    int b = blockIdx.x * GPB + g;
    const bool valid = (b < B);
    b = valid ? b : (B - 1);

    const float* arow = attention + (size_t)b * MM;
    const float4* brow4 = reinterpret_cast<const float4*>(boxes + (size_t)b * (4 * MM));

    // ---- issue coalesced global loads first ----
    float v0 = arow[l];
    float v1 = arow[l + 16];
    float v2 = -INFINITY;
    if (l < 4) v2 = arow[l + 32];
    float4 B0 = brow4[l];
    float4 B1 = brow4[l + 16];
    float4 B2 = make_float4(0.f, 0.f, 0.f, 0.f);
    if (l < 4) B2 = brow4[l + 32];

    // ---- stage box row into LDS early (kills B0..B2 live ranges; wave-local) ----
    float4* bls = reinterpret_cast<float4*>(&boxrow[g][0]);
    bls[l] = B0;
    bls[l + 16] = B1;
    if (l < 4) bls[l + 32] = B2;

    // ---- per-wave table build (lanes 0..7; f3,f4 dead; div-free; one live array) ----
    if (lane < 8 && lane != 3 && lane != 4) {
        const float* wp = fw + lane * 17;
        float aw[17];
        float s = 0.f;
        #pragma unroll
        for (int k = 0; k < 17; ++k) { aw[k] = fabsf(wp[k]); s += aw[k]; }
        float is = __fdividef(1.0f, s);

        if (lane == 1 || lane == 6) {
            float* dst = &T16w[w][0].x + ((lane == 1) ? 0 : 2);
            float c = 0.f;
            #pragma unroll
            for (int k = 0; k < 17; ++k) {
                float nwk = aw[k] * is;
                c += nwk;
                dst[4 * k]     = c;
                dst[4 * k + 1] = ((k < 16) ? aw[k + 1] : aw[16]) * is;
            }
        } else {
            int row = (lane == 0) ? 0 : (lane == 2) ? 1 : (lane == 5) ? 2 : 3;
            float c = 0.f;
            #pragma unroll
            for (int k = 0; k < 17; ++k) {
                float nwk = aw[k] * is;
                c += nwk;
                Tw[w][row][k] = make_float2(c, ((k < 16) ? aw[k + 1] : aw[16]) * is);
            }
        }
    }

    // ---- top-10: DPP max + ballot argmax; lane t captures (index,value) ----
    const int gbase = tid & 48;   // == (lane & 48): bits 4,5 identical
    int mi = 0; float mv = 0.f;
    #pragma unroll
    for (int t = 0; t < NP; ++t) {
        float vm = rowmax16(fmaxf(fmaxf(v0, v1), v2));
        unsigned long long b0 = __ballot(v0 == vm);
        unsigned long long b1 = __ballot(v1 == vm);
        unsigned long long b2 = __ballot(v2 == vm);
        unsigned g0 = (unsigned)(b0 >> gbase) & 0xFFFFu;
        unsigned g1 = (unsigned)(b1 >> gbase) & 0xFFFFu;
        unsigned g2 = (unsigned)(b2 >> gbase) & 0xFFFFu;
        int m = g0 ? (__ffs(g0) - 1)
              : (g1 ? (__ffs(g1) + 15)
                    : (__ffs(g2) + 31));
        if (l == t) { mi = m; mv = vm; }
        v0 = (m == l)      ? -INFINITY : v0;
        v1 = (m == l + 16) ? -INFINITY : v1;
        v2 = (m == l + 32) ? -INFINITY : v2;
    }

    // ---- lane i owns proposal i: gather coords from LDS, stage group data ----
    float sattI = 0.f, y1I = 0.f, x1I = 0.f, y2I = 0.f, x2I = 0.f, areaI = 0.f;
    if (l < NP) {
        sattI = 1.0f / (1.0f + __expf(-mv));
        y1I = boxrow[g][mi];
        x1I = boxrow[g][mi + MM];
        y2I = boxrow[g][mi + 2 * MM];
        x2I = boxrow[g][mi + 3 * MM];
        areaI = fmaxf(y2I - y1I, 0.f) * fmaxf(x2I - x1I, 0.f);
        propA[g][l] = make_float4(y1I, x1I, y2I, x2I);
        propB[g][l] = make_float2(areaI, sattI);
    }

    const float2* T0 = &Tw[w][0][0];
    const float2* T2 = &Tw[w][1][0];
    const float2* T5 = &Tw[w][2][0];
    const float2* T7 = &Tw[w][3][0];
    const float4* T16 = &T16w[w][0];

    float cs2_16 = T2[16].x;        // f2(1.0); zero-score_diff prod == cs2_16^10
    float p2c = cs2_16 * cs2_16;
    float p4c = p2c * p2c;
    float p8c = p4c * p4c;
    float P = p8c * p2c;

    // ---- pair loop: lane i vs all j (broadcast LDS reads) ----
    float at[NP];
    float s_um = 0.f, pdAcc = 0.f;
    #pragma unroll
    for (int j = 0; j < NP; ++j) {
        float4 pj = propA[g][j];
        float2 qj = propB[g][j];
        float ty = fmaxf(y1I, pj.x);
        float tx = fmaxf(x1I, pj.y);
        float by = fminf(y2I, pj.z);
        float bx = fminf(x2I, pj.w);
        float inter = fmaxf(by - ty, 0.f) * fmaxf(bx - tx, 0.f);
        float iouv = __fdividef(inter, areaI + qj.x - inter + 1e-12f);
        float Dm = fmaxf(1.0f - iouv, 0.0f);
        float A = sattI * qj.y;
        // shared-x eval of f1 and f6 from packed float4 table
        float xdD = Dm * 16.0f;
        float fipD = fminf(floorf(xdD), 16.0f);
        float frD = xdD - fipD;
        float4 t16 = T16[(int)fipD];
        float f1v = fmaf(frD, t16.y, t16.x);
        float f6v = fabsf(fmaf(frD, t16.w, t16.z) - 0.5f);
        at[j] = pwl17(T0, A) * f1v;
        s_um += pwl17(T2, 1.0f - fabsf(sattI - qj.y));
        pdAcc += f6v;
    }
    float s_i = s_um * P;

    float inv_i = 1.0f / s_i;
    if (l < NP) invl[g][l] = inv_i;

    float dot = 0.f;
    const float2* ivp = reinterpret_cast<const float2*>(&invl[g][0]);
    #pragma unroll
    for (int jj = 0; jj < NP / 2; ++jj) {
        float2 iv = ivp[jj];
        dot = fmaf(at[2 * jj], iv.x, dot);
        dot = fmaf(at[2 * jj + 1], iv.y, dot);
    }

    float corr = pwl17(T0, sattI * sattI) * inv_i;
    float fmask = (l < NP) ? 1.f : 0.f;
    float contrib = fmask * (inv_i * dot + corr);
    float pav = fmask * fabsf(pwl17(T5, sattI) - 0.5f);
    float pdv = fmask * pdAcc;

    contrib = rowsum16(contrib);
    pav = rowsum16(pav);
    pdv = rowsum16(pdv);

    // ---- epilogue ----
    float gate = pwl17(T7, pav * 0.1f + pdv * 0.01f);
    float cval = sqrtf(contrib + 1e-20f);
    cval = fminf(fmaxf(cval, 0.f), 10.0f);
    float fip = floorf(cval);
    int ipc = (int)fip;
    float frac = cval - fip;
    int i0 = ipc < 10 ? ipc : 10;
    int i1 = (ipc + 1) < 10 ? (ipc + 1) : 10;

    if (valid && l < NP + 1) {
        float val = ((l == i0) ? (1.0f - frac) * gate : 0.f)
                  + ((l == i1) ? frac * gate : 0.f);
        out[(size_t)b * (NP + 1) + l] = val;
    }
}

extern "C" void kernel_launch(void* const* d_in, const int* in_sizes, int n_in,
                              void* d_out, int out_size, void* d_ws, size_t ws_size,
                              hipStream_t stream) {
    const float* boxes = (const float*)d_in[0];
    const float* attention = (const float*)d_in[1];
    const float* fw = (const float*)d_in[2];
    float* out = (float*)d_out;
    int B = in_sizes[1] / MM;   // 32768
    int grid = (B + GPB - 1) / GPB;   // 512 workgroups
    hipLaunchKernelGGL(count_kernel, dim3(grid), dim3(BLOCK), 0, stream,
                       boxes, attention, fw, out, B);
}

// Round 8
// 23.763 us; speedup vs baseline: 1.1375x; 1.1375x over previous
//
#include <hip/hip_runtime.h>
#include <cstdint>
#include <cstddef>

#define MM 36
#define NP 10
#define BLOCK 256
#define GPB (BLOCK / 16)    // 16 batches (16-lane groups) per block
#define WPB (BLOCK / 64)    // 4 waves per block

// ---- DPP helpers: 16-lane butterfly reduce (VALU pipe, zero DS traffic) ----
template<int CTRL>
__device__ __forceinline__ float dpp_movf(float x) {
    return __int_as_float(__builtin_amdgcn_update_dpp(
        0, __float_as_int(x), CTRL, 0xF, 0xF, true));
}
__device__ __forceinline__ float rowmax16(float x) {
    x = fmaxf(x, dpp_movf<0xB1>(x));   // xor 1
    x = fmaxf(x, dpp_movf<0x4E>(x));   // xor 2
    x = fmaxf(x, dpp_movf<0x141>(x));  // row_half_mirror (fold 8)
    x = fmaxf(x, dpp_movf<0x140>(x));  // row_mirror      (fold 16)
    return x;
}
__device__ __forceinline__ float rowsum16(float x) {
    x += dpp_movf<0xB1>(x);
    x += dpp_movf<0x4E>(x);
    x += dpp_movf<0x141>(x);
    x += dpp_movf<0x140>(x);
    return x;
}

// x in [0,1]; 17-entry table (ip==16 only at x==1: frac==0, returns cs[16] exactly)
__device__ __forceinline__ float pwl17(const float2* __restrict__ T, float x) {
    float xd = x * 16.0f;
    float fip = floorf(xd);
    float frac = xd - fip;
    int ip = (int)fminf(fip, 16.0f);
    float2 t = T[ip];
    return fmaf(frac, t.y, t.x);
}

__global__ __launch_bounds__(BLOCK) void count_kernel(
    const float* __restrict__ boxes,      // [B,4,36]
    const float* __restrict__ attention,  // [B,36]
    const float* __restrict__ fw,         // [8,17]
    float* __restrict__ out,              // [B,11]
    int B)
{
    __shared__ float2 Tw[WPB][4][17];     // per-wave: f0, f2, f5, f7
    __shared__ float4 T16w[WPB][17];      // per-wave packed (cs1,nw1',cs6,nw6')
    __shared__ float4 propA[GPB][NP];     // y1,x1,y2,x2
    __shared__ float2 propB[GPB][NP];     // area, satt
    __shared__ __align__(16) float invl[GPB][NP];

    const int tid  = threadIdx.x;
    const int lane = tid & 63;
    const int w    = tid >> 6;
    const int l    = tid & 15;
    const int g    = tid >> 4;
    int b = blockIdx.x * GPB + g;
    const bool valid = (b < B);
    b = valid ? b : (B - 1);

    const float* arow = attention + (size_t)b * MM;
    const float* brow = boxes + (size_t)b * (4 * MM);

    // ---- coalesced attention loads (issue first) ----
    float v0 = arow[l];
    float v1 = arow[l + 16];
    float v2 = -INFINITY;
    if (l < 4) v2 = arow[l + 32];

    // ---- per-wave table build: ONE unified write loop, 17 ds_write_b64 total ----
    if (lane < 8 && lane != 3 && lane != 4) {
        const float* wp = fw + lane * 17;
        float aw[17];
        float s = 0.f;
        #pragma unroll
        for (int k = 0; k < 17; ++k) { aw[k] = fabsf(wp[k]); s += aw[k]; }
        float is = __fdividef(1.0f, s);

        // dest base & element stride (float2 units); branch is side-effect-free -> selects
        float2* base;
        int str;
        if (lane == 1)      { base = reinterpret_cast<float2*>(&T16w[w][0]);     str = 2; }
        else if (lane == 6) { base = reinterpret_cast<float2*>(&T16w[w][0]) + 1; str = 2; }
        else {
            int row = (lane == 0) ? 0 : (lane == 2) ? 1 : (lane == 5) ? 2 : 3;
            base = &Tw[w][row][0]; str = 1;
        }
        float c = 0.f;
        #pragma unroll
        for (int k = 0; k < 17; ++k) {
            float nwk = aw[k] * is;
            c += nwk;
            base[k * str] = make_float2(c, ((k < 16) ? aw[k + 1] : aw[16]) * is);
        }
    }

    // ---- top-10: DPP max + ballot argmax; lane t captures (index,value) ----
    const int gbase = tid & 48;
    int mi = 0; float mv = 0.f;
    #pragma unroll
    for (int t = 0; t < NP; ++t) {
        float vm = rowmax16(fmaxf(fmaxf(v0, v1), v2));
        unsigned long long b0 = __ballot(v0 == vm);
        unsigned long long b1 = __ballot(v1 == vm);
        unsigned long long b2 = __ballot(v2 == vm);
        unsigned g0 = (unsigned)(b0 >> gbase) & 0xFFFFu;
        unsigned g1 = (unsigned)(b1 >> gbase) & 0xFFFFu;
        unsigned g2 = (unsigned)(b2 >> gbase) & 0xFFFFu;
        int m = g0 ? (__ffs(g0) - 1)
              : (g1 ? (__ffs(g1) + 15)
                    : (__ffs(g2) + 31));
        if (l == t) { mi = m; mv = vm; }
        v0 = (m == l)      ? -INFINITY : v0;
        v1 = (m == l + 16) ? -INFINITY : v1;
        v2 = (m == l + 32) ? -INFINITY : v2;
    }

    // ---- lane i owns proposal i: 4 scattered global loads (TA pipe, L2-warm) ----
    float sattI = 0.f, y1I = 0.f, x1I = 0.f, y2I = 0.f, x2I = 0.f, areaI = 0.f;
    if (l < NP) {
        sattI = 1.0f / (1.0f + __expf(-mv));
        y1I = brow[mi];
        x1I = brow[mi + MM];
        y2I = brow[mi + 2 * MM];
        x2I = brow[mi + 3 * MM];
        areaI = fmaxf(y2I - y1I, 0.f) * fmaxf(x2I - x1I, 0.f);
        propA[g][l] = make_float4(y1I, x1I, y2I, x2I);
        propB[g][l] = make_float2(areaI, sattI);
    }
    // wave-local LDS: same-wave DS ordering via lgkmcnt, no barrier

    const float2* T0 = &Tw[w][0][0];
    const float2* T2 = &Tw[w][1][0];
    const float2* T5 = &Tw[w][2][0];
    const float2* T7 = &Tw[w][3][0];
    const float4* T16 = &T16w[w][0];

    float cs2_16 = T2[16].x;        // f2(1.0); zero-score_diff prod == cs2_16^10
    float p2c = cs2_16 * cs2_16;
    float p4c = p2c * p2c;
    float p8c = p4c * p4c;
    float P = p8c * p2c;

    // ---- pair loop: lane i vs all j (broadcast LDS reads) ----
    float at[NP];
    float s_um = 0.f, pdAcc = 0.f;
    #pragma unroll
    for (int j = 0; j < NP; ++j) {
        float4 pj = propA[g][j];
        float2 qj = propB[g][j];
        float ty = fmaxf(y1I, pj.x);
        float tx = fmaxf(x1I, pj.y);
        float by = fminf(y2I, pj.z);
        float bx = fminf(x2I, pj.w);
        float inter = fmaxf(by - ty, 0.f) * fmaxf(bx - tx, 0.f);
        float iouv = __fdividef(inter, areaI + qj.x - inter + 1e-12f);
        float Dm = fmaxf(1.0f - iouv, 0.0f);
        float A = sattI * qj.y;
        // shared-x eval of f1 and f6 from packed float4 table
        float xdD = Dm * 16.0f;
        float fipD = fminf(floorf(xdD), 16.0f);
        float frD = xdD - fipD;
        float4 t16 = T16[(int)fipD];
        float f1v = fmaf(frD, t16.y, t16.x);
        float f6v = fabsf(fmaf(frD, t16.w, t16.z) - 0.5f);
        at[j] = pwl17(T0, A) * f1v;
        s_um += pwl17(T2, 1.0f - fabsf(sattI - qj.y));
        pdAcc += f6v;
    }
    float s_i = s_um * P;

    float inv_i = 1.0f / s_i;
    if (l < NP) invl[g][l] = inv_i;

    // vectorized broadcast read of all 10 inverses (2x b128 + 1x b64)
    const float4* f4p = reinterpret_cast<const float4*>(&invl[g][0]);
    float4 ivA = f4p[0];
    float4 ivB = f4p[1];
    float2 ivC = *reinterpret_cast<const float2*>(&invl[g][8]);

    float dot = 0.f;
    dot = fmaf(at[0], ivA.x, dot);
    dot = fmaf(at[1], ivA.y, dot);
    dot = fmaf(at[2], ivA.z, dot);
    dot = fmaf(at[3], ivA.w, dot);
    dot = fmaf(at[4], ivB.x, dot);
    dot = fmaf(at[5], ivB.y, dot);
    dot = fmaf(at[6], ivB.z, dot);
    dot = fmaf(at[7], ivB.w, dot);
    dot = fmaf(at[8], ivC.x, dot);
    dot = fmaf(at[9], ivC.y, dot);

    float corr = pwl17(T0, sattI * sattI) * inv_i;
    float fmask = (l < NP) ? 1.f : 0.f;
    float contrib = fmask * (inv_i * dot + corr);
    float pav = fmask * fabsf(pwl17(T5, sattI) - 0.5f);
    float pdv = fmask * pdAcc;

    contrib = rowsum16(contrib);
    pav = rowsum16(pav);
    pdv = rowsum16(pdv);

    // ---- epilogue ----
    float gate = pwl17(T7, pav * 0.1f + pdv * 0.01f);
    float cval = sqrtf(contrib + 1e-20f);
    cval = fminf(fmaxf(cval, 0.f), 10.0f);
    float fip = floorf(cval);
    int ipc = (int)fip;
    float frac = cval - fip;
    int i0 = ipc < 10 ? ipc : 10;
    int i1 = (ipc + 1) < 10 ? (ipc + 1) : 10;

    if (valid && l < NP + 1) {
        float val = ((l == i0) ? (1.0f - frac) * gate : 0.f)
                  + ((l == i1) ? frac * gate : 0.f);
        out[(size_t)b * (NP + 1) + l] = val;
    }
}

extern "C" void kernel_launch(void* const* d_in, const int* in_sizes, int n_in,
                              void* d_out, int out_size, void* d_ws, size_t ws_size,
                              hipStream_t stream) {
    const float* boxes = (const float*)d_in[0];
    const float* attention = (const float*)d_in[1];
    const float* fw = (const float*)d_in[2];
    float* out = (float*)d_out;
    int B = in_sizes[1] / MM;   // 32768
    int grid = (B + GPB - 1) / GPB;   // 2048 workgroups
    hipLaunchKernelGGL(count_kernel, dim3(grid), dim3(BLOCK), 0, stream,
                       boxes, attention, fw, out, B);
}